// Round 1
// baseline (1090.749 us; speedup 1.0000x reference)
//
#include <hip/hip_runtime.h>
#include <cstdint>
#include <cstddef>

// Shapes (fixed)
#define NBATCH 8
#define LSEQ   256
#define NODE_CNT 2048   // NBATCH*LSEQ

// workspace float offsets
#define OFF_HP      0u         // 2048*256
#define OFF_DP      524288u    // 2048*64
#define OFF_SI      655360u    // 2048*8
#define OFF_SJ      671744u    // 2048*8
#define OFF_WHH     688128u    // 2048*256
#define OFF_U       1212416u   // 2048*128
#define OFF_V       1474560u   // 2048*128
#define OFF_G       1736704u   // 128*8
#define OFF_CE      1737728u   // 8 (padded)
#define OFF_CT      1737760u   // 128*128
#define OFF_K0      1754144u   // 128
#define OFF_D       1754272u   // 128*128
#define OFF_CONSTE  1770656u   // 128
// total 1770784 floats = ~6.8 MB

__device__ __forceinline__ float lrelu(float x){ return x >= 0.f ? x : 0.2f*x; }

// ---------------- K0a: fold attention vector + phase-2 left chain ----------
__global__ void k_pre_a(const float* __restrict__ We_w, const float* __restrict__ We_b,
                        const float* __restrict__ attn_w,
                        const float* __restrict__ edge_lin_w, const float* __restrict__ edge_lin_b,
                        const float* __restrict__ We2_w, const float* __restrict__ We2_b,
                        float* __restrict__ ws) {
    int tid = threadIdx.x;
    const float* a_e = attn_w + 64;  // a[64:80]
    // G[k][h] = sum_e a_e[e]*We_w[h*16+e][k]
    for (int idx = tid; idx < 128*8; idx += 256) {
        int k = idx >> 3, h = idx & 7;
        float s = 0.f;
        for (int e = 0; e < 16; ++e) s += a_e[e] * We_w[(h*16+e)*128 + k];
        ws[OFF_G + k*8 + h] = s;
    }
    if (tid < 8) {
        float s = 0.f;
        for (int e = 0; e < 16; ++e) s += a_e[e] * We_b[tid*16+e];
        ws[OFF_CE + tid] = s;
    }
    // D[m=h*16+eo][k] = sum_ei W_e[eo][ei]*We2_w[h*16+ei][k]
    for (int idx = tid; idx < 128*128; idx += 256) {
        int m = idx >> 7, k = idx & 127;
        int h = m >> 4, eo = m & 15;
        float s = 0.f;
        for (int ei = 0; ei < 16; ++ei) s += edge_lin_w[eo*96 + ei] * We2_w[(h*16+ei)*128 + k];
        ws[OFF_D + m*128 + k] = s;
    }
    if (tid < 128) {
        int h = tid >> 4, eo = tid & 15;
        float s = edge_lin_b[eo];
        for (int ei = 0; ei < 16; ++ei) s += edge_lin_w[eo*96+ei] * We2_b[h*16+ei];
        ws[OFF_CONSTE + tid] = s;
    }
}

// ---------------- K0b: CT = (oute_w @ D)^T, k0 --------------------------
__global__ void k_pre_b(const float* __restrict__ oute_w, const float* __restrict__ oute_b,
                        float* __restrict__ ws) {
    int idx = blockIdx.x*256 + threadIdx.x;  // 0..16383
    int k = idx >> 7, n2 = idx & 127;
    const float* D = ws + OFF_D;
    float s = 0.f;
    for (int m = 0; m < 128; ++m) s += oute_w[n2*128+m] * D[m*128+k];
    ws[OFF_CT + k*128 + n2] = s;
    if (blockIdx.x == 0 && threadIdx.x < 128) {
        int n = threadIdx.x;
        float t = oute_b[n];
        const float* ce = ws + OFF_CONSTE;
        for (int m = 0; m < 128; ++m) t += oute_w[n*128+m]*ce[m];
        ws[OFF_K0 + n] = t;
    }
}

// ---------------- K1: per-node phase-1 projections (8 nodes/block) ------
__global__ void k_node1(const float* __restrict__ node, const float* __restrict__ diff,
                        const float* __restrict__ Wn_w, const float* __restrict__ Wn_b,
                        const float* __restrict__ Wd_w, const float* __restrict__ Wd_b,
                        const float* __restrict__ Wh_w, const float* __restrict__ Wh_b,
                        const float* __restrict__ attn_w, float* __restrict__ ws) {
    __shared__ float nrow[8][256];
    __shared__ float drow[8][64];
    __shared__ float hprow[8][256];
    __shared__ float dprow[8][64];
    int tid = threadIdx.x;
    int n0 = blockIdx.x * 8;
    for (int t = 0; t < 8; ++t) nrow[t][tid] = node[(size_t)(n0+t)*256 + tid];
    if (tid < 64) for (int t = 0; t < 8; ++t) drow[t][tid] = diff[(n0+t)*64 + tid];
    __syncthreads();
    {   // hp = node @ Wn_w^T + b
        float acc[8];
        #pragma unroll
        for (int t = 0; t < 8; ++t) acc[t] = Wn_b[tid];
        const float* wr = Wn_w + tid*256;
        for (int k = 0; k < 256; ++k) {
            float w = wr[k];
            #pragma unroll
            for (int t = 0; t < 8; ++t) acc[t] += nrow[t][k]*w;
        }
        #pragma unroll
        for (int t = 0; t < 8; ++t) { ws[OFF_HP + (size_t)(n0+t)*256 + tid] = acc[t]; hprow[t][tid] = acc[t]; }
    }
    if (tid < 64) {  // dp = diff @ Wd_w^T + b
        float acc[8];
        #pragma unroll
        for (int t = 0; t < 8; ++t) acc[t] = Wd_b[tid];
        const float* wr = Wd_w + tid*64;
        for (int k = 0; k < 64; ++k) {
            float w = wr[k];
            #pragma unroll
            for (int t = 0; t < 8; ++t) acc[t] += drow[t][k]*w;
        }
        #pragma unroll
        for (int t = 0; t < 8; ++t) { ws[OFF_DP + (n0+t)*64 + tid] = acc[t]; dprow[t][tid] = acc[t]; }
    }
    __syncthreads();
    {   // whh[h][d] = hp[h] @ Wh_w^T + b
        int h = tid >> 5, d = tid & 31;
        float acc[8];
        #pragma unroll
        for (int t = 0; t < 8; ++t) acc[t] = Wh_b[d];
        const float* wr = Wh_w + d*32;
        for (int k = 0; k < 32; ++k) {
            float w = wr[k];
            #pragma unroll
            for (int t = 0; t < 8; ++t) acc[t] += hprow[t][h*32+k]*w;
        }
        #pragma unroll
        for (int t = 0; t < 8; ++t) ws[OFF_WHH + (size_t)(n0+t)*256 + tid] = acc[t];
    }
    if (tid < 16) {  // s_i / s_j
        int h = tid & 7; bool isj = tid >= 8;
        const float* ah = attn_w + (isj ? 32 : 0);
        const float* ad = attn_w + (isj ? 88 : 80);
        for (int t = 0; t < 8; ++t) {
            float s = 0.f;
            for (int k = 0; k < 32; ++k) s += hprow[t][h*32+k]*ah[k];
            for (int k = 0; k < 8;  ++k) s += dprow[t][h*8+k]*ad[k];
            ws[(isj ? OFF_SJ : OFF_SI) + (n0+t)*8 + h] = s;
        }
    }
}

// ---------------- K2: fused phase-1 row kernel (block per (b,i)) --------
#define SC_PITCH 264
__global__ __launch_bounds__(256)
void k_phase1(const float* __restrict__ edge, float* __restrict__ ws,
              const float* __restrict__ outn_w, const float* __restrict__ outn_b,
              float* __restrict__ out_node) {
    __shared__ float sc[8*SC_PITCH];
    __shared__ float Gs[1024];
    __shared__ float cEs[8], sirow[8], hinv[8];
    __shared__ float hprow[256];
    __shared__ float arow[256];
    int tid = threadIdx.x;
    int bl = blockIdx.x;           // b*256 + i
    int i = bl & 255;
    int base_b = bl & ~255;
    for (int idx = tid; idx < 1024; idx += 256) Gs[idx] = ws[OFF_G + idx];
    if (tid < 8) { cEs[tid] = ws[OFF_CE + tid]; sirow[tid] = ws[OFF_SI + bl*8 + tid]; }
    hprow[tid] = ws[OFF_HP + (size_t)bl*256 + tid];
    __syncthreads();

    int jj = tid >> 3, h = tid & 7;
    const float* erow = edge + (size_t)bl*256*128;
    const float* sj = ws + OFF_SJ;
    for (int t = 0; t < 8; ++t) {
        int j = t*32 + jj;
        const float* ev = erow + (size_t)j*128;
        float s = cEs[h];
        for (int k = 0; k < 128; k += 4) {
            float4 e4 = *(const float4*)(ev + k);
            s += e4.x*Gs[(k  )*8+h] + e4.y*Gs[(k+1)*8+h]
               + e4.z*Gs[(k+2)*8+h] + e4.w*Gs[(k+3)*8+h];
        }
        s += sirow[h] + sj[(base_b + j)*8 + h];
        s = lrelu(s);
        if (j == i) s = -3.4028235e38f;
        sc[h*SC_PITCH + j] = s;
    }
    __syncthreads();
    {   // softmax over j per head; 32 lanes per head
        int g = tid >> 5, lane = tid & 31;
        float m = -3.4028235e38f;
        for (int t = 0; t < 8; ++t) m = fmaxf(m, sc[g*SC_PITCH + lane + 32*t]);
        for (int off = 16; off >= 1; off >>= 1) m = fmaxf(m, __shfl_xor(m, off, 32));
        float ssum = 0.f;
        for (int t = 0; t < 8; ++t) {
            int j = lane + 32*t;
            float e = __expf(sc[g*SC_PITCH + j] - m);
            sc[g*SC_PITCH + j] = e;
            ssum += e;
        }
        for (int off = 16; off >= 1; off >>= 1) ssum += __shfl_xor(ssum, off, 32);
        if (lane == 0) hinv[g] = 1.f/ssum;
    }
    __syncthreads();
    {   // agg + residual + lrelu
        int hh = tid >> 5;
        const float* whh = ws + OFF_WHH + (size_t)base_b*256;
        float acc = 0.f;
        for (int j = 0; j < 256; ++j) acc += sc[hh*SC_PITCH + j]*whh[(size_t)j*256 + tid];
        acc *= hinv[hh];
        arow[tid] = hprow[tid] + lrelu(acc);
    }
    __syncthreads();
    {   // new_node = arow @ outn_w^T + b
        float o = outn_b[tid];
        const float* wr = outn_w + tid*256;
        for (int m = 0; m < 256; ++m) o += arow[m]*wr[m];
        out_node[(size_t)bl*256 + tid] = o;
    }
}

// ---------------- K3: phase-2 node precompute (8 nodes/block) -----------
__global__ void k_node2(const float* __restrict__ out_node, const float* __restrict__ diff,
                        const float* __restrict__ Wn2_w, const float* __restrict__ Wn2_b,
                        const float* __restrict__ Wd2_w, const float* __restrict__ Wd2_b,
                        const float* __restrict__ edge_lin_w, const float* __restrict__ oute_w,
                        float* __restrict__ ws) {
    __shared__ float nrow[8][256];
    __shared__ float drow[8][64];
    __shared__ float hp2[8][256];
    __shared__ float dp2[8][64];
    __shared__ float tij[2][8][128];
    int tid = threadIdx.x;
    int n0 = blockIdx.x * 8;
    for (int t = 0; t < 8; ++t) nrow[t][tid] = out_node[(size_t)(n0+t)*256 + tid];
    if (tid < 64) for (int t = 0; t < 8; ++t) drow[t][tid] = diff[(n0+t)*64 + tid];
    __syncthreads();
    {
        float acc[8];
        #pragma unroll
        for (int t = 0; t < 8; ++t) acc[t] = Wn2_b[tid];
        const float* wr = Wn2_w + tid*256;
        for (int k = 0; k < 256; ++k) {
            float w = wr[k];
            #pragma unroll
            for (int t = 0; t < 8; ++t) acc[t] += nrow[t][k]*w;
        }
        #pragma unroll
        for (int t = 0; t < 8; ++t) hp2[t][tid] = acc[t];
    }
    if (tid < 64) {
        float acc[8];
        #pragma unroll
        for (int t = 0; t < 8; ++t) acc[t] = Wd2_b[tid];
        const float* wr = Wd2_w + tid*64;
        for (int k = 0; k < 64; ++k) {
            float w = wr[k];
            #pragma unroll
            for (int t = 0; t < 8; ++t) acc[t] += drow[t][k]*w;
        }
        #pragma unroll
        for (int t = 0; t < 8; ++t) dp2[t][tid] = acc[t];
    }
    __syncthreads();
    // t_i (s=0) / t_j (s=1): 2*8nodes*128m entries
    for (int q = 0; q < 8; ++q) {
        int idx = q*256 + tid;
        int s = idx >> 10; int r = idx & 1023; int t = r >> 7; int m = r & 127;
        int h = m >> 4, eo = m & 15;
        const float* wh = edge_lin_w + eo*96 + (s ? 48 : 16);
        const float* wd = edge_lin_w + eo*96 + (s ? 88 : 80);
        float v = 0.f;
        for (int d = 0; d < 32; ++d) v += hp2[t][h*32+d]*wh[d];
        for (int d = 0; d < 8;  ++d) v += dp2[t][h*8+d]*wd[d];
        tij[s][t][m] = v;
    }
    __syncthreads();
    // u = t_i @ oute_w^T ; v = t_j @ oute_w^T
    for (int q = 0; q < 8; ++q) {
        int idx = q*256 + tid;
        int s = idx >> 10; int r = idx & 1023; int t = r >> 7; int n2 = r & 127;
        const float* wr = oute_w + n2*128;
        const float* tv = tij[s][t];
        float acc = 0.f;
        for (int m = 0; m < 128; ++m) acc += wr[m]*tv[m];
        ws[(s ? OFF_V : OFF_U) + (n0+t)*128 + n2] = acc;
    }
}

// ---------------- K4: new_edge = edge@CT + u + v + k0 (diag -> oute_b) --
#define KKSTEP(F, KOFF) { \
    float4 b0 = *(const float4*)&CTs[(kq+KOFF)*128 + n2b]; \
    float4 b1 = *(const float4*)&CTs[(kq+KOFF)*128 + n2b + 4]; \
    _Pragma("unroll") \
    for (int p = 0; p < 8; ++p) { float av = a4[p].F; \
        acc[p][0] += av*b0.x; acc[p][1] += av*b0.y; acc[p][2] += av*b0.z; acc[p][3] += av*b0.w; \
        acc[p][4] += av*b1.x; acc[p][5] += av*b1.y; acc[p][6] += av*b1.z; acc[p][7] += av*b1.w; } }

__global__ __launch_bounds__(256, 2)
void k_edge2(const float* __restrict__ edge, const float* __restrict__ oute_b,
             const float* __restrict__ ws, float* __restrict__ out_edge) {
    __shared__ float CTs[128*128];   // 64 KB
    int tid = threadIdx.x;
    int bx = blockIdx.x;
    int bl = bx >> 1, jh = bx & 1;   // bl = b*256+i ; jh = j-half
    int i = bl & 255, base_b = bl & ~255;
    for (int idx = tid; idx < 16384; idx += 256) CTs[idx] = ws[OFF_CT + idx];
    __syncthreads();
    int tj = tid >> 4, tn = tid & 15;
    int n2b = tn*8;
    const float* erow = edge + (size_t)bl*256*128 + (size_t)(jh*128 + tj*8)*128;
    float acc[8][8];
    #pragma unroll
    for (int p = 0; p < 8; ++p)
        #pragma unroll
        for (int q = 0; q < 8; ++q) acc[p][q] = 0.f;

    for (int kq = 0; kq < 128; kq += 4) {
        float4 a4[8];
        #pragma unroll
        for (int p = 0; p < 8; ++p) a4[p] = *(const float4*)(erow + (size_t)p*128 + kq);
        KKSTEP(x, 0) KKSTEP(y, 1) KKSTEP(z, 2) KKSTEP(w, 3)
    }

    const float* uP = ws + OFF_U + (size_t)bl*128 + n2b;
    float4 u0 = *(const float4*)uP, u1 = *(const float4*)(uP+4);
    const float* cP = ws + OFF_K0 + n2b;
    float4 c0 = *(const float4*)cP, c1 = *(const float4*)(cP+4);
    float4 ob0 = *(const float4*)(oute_b + n2b), ob1 = *(const float4*)(oute_b + n2b + 4);
    #pragma unroll
    for (int p = 0; p < 8; ++p) {
        int j = jh*128 + tj*8 + p;
        const float* vP = ws + OFF_V + (size_t)(base_b + j)*128 + n2b;
        float4 v0 = *(const float4*)vP, v1 = *(const float4*)(vP+4);
        float4 o0, o1;
        o0.x = acc[p][0]+u0.x+v0.x+c0.x; o0.y = acc[p][1]+u0.y+v0.y+c0.y;
        o0.z = acc[p][2]+u0.z+v0.z+c0.z; o0.w = acc[p][3]+u0.w+v0.w+c0.w;
        o1.x = acc[p][4]+u1.x+v1.x+c1.x; o1.y = acc[p][5]+u1.y+v1.y+c1.y;
        o1.z = acc[p][6]+u1.z+v1.z+c1.z; o1.w = acc[p][7]+u1.w+v1.w+c1.w;
        if (j == i) { o0 = ob0; o1 = ob1; }
        float* oP = out_edge + ((size_t)bl*256 + j)*128 + n2b;
        *(float4*)oP = o0; *(float4*)(oP+4) = o1;
    }
}

// ---------------- launch ------------------------------------------------
extern "C" void kernel_launch(void* const* d_in, const int* in_sizes, int n_in,
                              void* d_out, int out_size, void* d_ws, size_t ws_size,
                              hipStream_t stream) {
    const float* node   = (const float*)d_in[0];
    const float* edge   = (const float*)d_in[1];
    const float* diff   = (const float*)d_in[2];
    const float* Wn_w   = (const float*)d_in[3];
    const float* Wn_b   = (const float*)d_in[4];
    const float* Wh_w   = (const float*)d_in[5];
    const float* Wh_b   = (const float*)d_in[6];
    const float* We_w   = (const float*)d_in[7];
    const float* We_b   = (const float*)d_in[8];
    const float* Wn2_w  = (const float*)d_in[9];
    const float* Wn2_b  = (const float*)d_in[10];
    const float* We2_w  = (const float*)d_in[11];
    const float* We2_b  = (const float*)d_in[12];
    const float* Wd_w   = (const float*)d_in[13];
    const float* Wd_b   = (const float*)d_in[14];
    const float* Wd2_w  = (const float*)d_in[15];
    const float* Wd2_b  = (const float*)d_in[16];
    const float* attn_w = (const float*)d_in[17];
    const float* elw    = (const float*)d_in[18];
    const float* elb    = (const float*)d_in[19];
    const float* outn_w = (const float*)d_in[20];
    const float* outn_b = (const float*)d_in[21];
    const float* oute_w = (const float*)d_in[22];
    const float* oute_b = (const float*)d_in[23];
    float* ws = (float*)d_ws;
    float* out_node = (float*)d_out;
    float* out_edge = out_node + (size_t)NODE_CNT*256;

    k_pre_a<<<1, 256, 0, stream>>>(We_w, We_b, attn_w, elw, elb, We2_w, We2_b, ws);
    k_pre_b<<<64, 256, 0, stream>>>(oute_w, oute_b, ws);
    k_node1<<<256, 256, 0, stream>>>(node, diff, Wn_w, Wn_b, Wd_w, Wd_b, Wh_w, Wh_b, attn_w, ws);
    k_phase1<<<NODE_CNT, 256, 0, stream>>>(edge, ws, outn_w, outn_b, out_node);
    k_node2<<<256, 256, 0, stream>>>(out_node, diff, Wn2_w, Wn2_b, Wd2_w, Wd2_b, elw, oute_w, ws);
    k_edge2<<<NODE_CNT*2, 256, 0, stream>>>(edge, oute_b, ws, out_edge);
}

// Round 2
// 917.041 us; speedup vs baseline: 1.1894x; 1.1894x over previous
//
#include <hip/hip_runtime.h>
#include <cstdint>
#include <cstddef>

// Shapes (fixed)
#define NBATCH 8
#define LSEQ   256
#define NODE_CNT 2048   // NBATCH*LSEQ

// workspace float offsets
#define OFF_HP      0u         // 2048*256
#define OFF_DP      524288u    // 2048*64
#define OFF_SI      655360u    // 2048*8
#define OFF_SJ      671744u    // 2048*8
#define OFF_WHH     688128u    // 2048*256
#define OFF_U       1212416u   // 2048*128
#define OFF_V       1474560u   // 2048*128
#define OFF_CE      1737728u   // 8 (padded)
#define OFF_CT      1737760u   // 128*128
#define OFF_K0      1754144u   // 128
#define OFF_D       1754272u   // 128*128
#define OFF_CONSTE  1770656u   // 128
#define OFF_GT      1770784u   // 8*132 (G transposed, padded pitch)
#define OFF_WN1T    1771840u   // 256*256 Wn_w^T
#define OFF_WN2T    1837376u   // 256*256 Wn2_w^T
#define OFF_WNT     1902912u   // 256*256 outn_w^T
#define OFF_OUTET   1968448u   // 128*128 oute_w^T
#define OFF_WD1T    1984832u   // 64*64
#define OFF_WD2T    1988928u   // 64*64
#define OFF_WHT     1993024u   // 32*32
// total 1994048 floats ~= 8.0 MB

#define GT_PITCH 132
#define SC_PITCH 264

__device__ __forceinline__ float lrelu(float x){ return x >= 0.f ? x : 0.2f*x; }

// ---------------- K0a: fold attention vector + phase-2 left chain ----------
__global__ void k_pre_a(const float* __restrict__ We_w, const float* __restrict__ We_b,
                        const float* __restrict__ attn_w,
                        const float* __restrict__ edge_lin_w, const float* __restrict__ edge_lin_b,
                        const float* __restrict__ We2_w, const float* __restrict__ We2_b,
                        float* __restrict__ ws) {
    int tid = threadIdx.x;
    const float* a_e = attn_w + 64;  // a[64:80]
    // GT[h][k] = sum_e a_e[e]*We_w[h*16+e][k]   (padded pitch 132)
    for (int idx = tid; idx < 128*8; idx += 256) {
        int k = idx >> 3, h = idx & 7;
        float s = 0.f;
        for (int e = 0; e < 16; ++e) s += a_e[e] * We_w[(h*16+e)*128 + k];
        ws[OFF_GT + h*GT_PITCH + k] = s;
    }
    if (tid < 8) {
        float s = 0.f;
        for (int e = 0; e < 16; ++e) s += a_e[e] * We_b[tid*16+e];
        ws[OFF_CE + tid] = s;
    }
    // D[m=h*16+eo][k] = sum_ei W_e[eo][ei]*We2_w[h*16+ei][k]
    for (int idx = tid; idx < 128*128; idx += 256) {
        int m = idx >> 7, k = idx & 127;
        int h = m >> 4, eo = m & 15;
        float s = 0.f;
        for (int ei = 0; ei < 16; ++ei) s += edge_lin_w[eo*96 + ei] * We2_w[(h*16+ei)*128 + k];
        ws[OFF_D + m*128 + k] = s;
    }
    if (tid < 128) {
        int h = tid >> 4, eo = tid & 15;
        float s = edge_lin_b[eo];
        for (int ei = 0; ei < 16; ++ei) s += edge_lin_w[eo*96+ei] * We2_b[h*16+ei];
        ws[OFF_CONSTE + tid] = s;
    }
}

// ---------------- K0b: CT = (oute_w @ D)^T, k0 --------------------------
__global__ void k_pre_b(const float* __restrict__ oute_w, const float* __restrict__ oute_b,
                        float* __restrict__ ws) {
    int idx = blockIdx.x*256 + threadIdx.x;  // 0..16383
    int k = idx >> 7, n2 = idx & 127;
    const float* D = ws + OFF_D;
    float s = 0.f;
    for (int m = 0; m < 128; ++m) s += oute_w[n2*128+m] * D[m*128+k];
    ws[OFF_CT + k*128 + n2] = s;
    if (blockIdx.x == 0 && threadIdx.x < 128) {
        int n = threadIdx.x;
        float t = oute_b[n];
        const float* ce = ws + OFF_CONSTE;
        for (int m = 0; m < 128; ++m) t += oute_w[n*128+m]*ce[m];
        ws[OFF_K0 + n] = t;
    }
}

// ---------------- K0c: weight transposes --------------------------------
__global__ void k_transpose(const float* __restrict__ Wn_w, const float* __restrict__ Wn2_w,
                            const float* __restrict__ outn_w, const float* __restrict__ oute_w,
                            const float* __restrict__ Wd_w, const float* __restrict__ Wd2_w,
                            const float* __restrict__ Wh_w, float* __restrict__ ws) {
    int bx = blockIdx.x, tid = threadIdx.x;
    const float* src; float* dst; int ln, base;
    if      (bx < 256) { src = Wn_w;   dst = ws + OFF_WN1T;  ln = 8; base = bx; }
    else if (bx < 512) { src = Wn2_w;  dst = ws + OFF_WN2T;  ln = 8; base = bx - 256; }
    else if (bx < 768) { src = outn_w; dst = ws + OFF_WNT;   ln = 8; base = bx - 512; }
    else if (bx < 832) { src = oute_w; dst = ws + OFF_OUTET; ln = 7; base = bx - 768; }
    else if (bx < 848) { src = Wd_w;   dst = ws + OFF_WD1T;  ln = 6; base = bx - 832; }
    else if (bx < 864) { src = Wd2_w;  dst = ws + OFF_WD2T;  ln = 6; base = bx - 848; }
    else               { src = Wh_w;   dst = ws + OFF_WHT;   ln = 5; base = bx - 864; }
    int idx = base*256 + tid;
    int N = 1 << ln;
    int k = idx >> ln, n = idx & (N-1);
    dst[idx] = src[n*N + k];     // dst[k*N+n] = src[n][k]
}

// ---------------- K1: per-node phase-1 projections (8 nodes/block) ------
__global__ __launch_bounds__(256)
void k_node1(const float* __restrict__ node, const float* __restrict__ diff,
             const float* __restrict__ Wn_b, const float* __restrict__ Wd_b,
             const float* __restrict__ Wh_b, const float* __restrict__ attn_w,
             float* __restrict__ ws) {
    __shared__ float nrow[8][256];
    __shared__ float drow[8][64];
    __shared__ float hprow[8][256];
    __shared__ float dprow[8][64];
    int tid = threadIdx.x;
    int n0 = blockIdx.x * 8;
    #pragma unroll
    for (int t = 0; t < 8; ++t) nrow[t][tid] = node[(size_t)(n0+t)*256 + tid];
    if (tid < 64) {
        #pragma unroll
        for (int t = 0; t < 8; ++t) drow[t][tid] = diff[(n0+t)*64 + tid];
    }
    __syncthreads();
    {   // hp = node @ Wn_w^T + b  (WT coalesced, nrow broadcast)
        const float* WT = ws + OFF_WN1T;
        float acc[8] = {0,0,0,0,0,0,0,0};
        for (int k = 0; k < 256; k += 4) {
            float w0 = WT[(k  )*256+tid], w1 = WT[(k+1)*256+tid];
            float w2 = WT[(k+2)*256+tid], w3 = WT[(k+3)*256+tid];
            #pragma unroll
            for (int t = 0; t < 8; ++t) {
                float4 n4 = *(const float4*)&nrow[t][k];
                acc[t] += n4.x*w0 + n4.y*w1 + n4.z*w2 + n4.w*w3;
            }
        }
        float b = Wn_b[tid];
        #pragma unroll
        for (int t = 0; t < 8; ++t) {
            float v = acc[t] + b;
            ws[OFF_HP + (size_t)(n0+t)*256 + tid] = v;
            hprow[t][tid] = v;
        }
    }
    if (tid < 64) {  // dp = diff @ Wd_w^T + b
        const float* WT = ws + OFF_WD1T;
        float acc[8] = {0,0,0,0,0,0,0,0};
        for (int k = 0; k < 64; k += 4) {
            float w0 = WT[(k  )*64+tid], w1 = WT[(k+1)*64+tid];
            float w2 = WT[(k+2)*64+tid], w3 = WT[(k+3)*64+tid];
            #pragma unroll
            for (int t = 0; t < 8; ++t) {
                float4 d4 = *(const float4*)&drow[t][k];
                acc[t] += d4.x*w0 + d4.y*w1 + d4.z*w2 + d4.w*w3;
            }
        }
        float b = Wd_b[tid];
        #pragma unroll
        for (int t = 0; t < 8; ++t) {
            float v = acc[t] + b;
            ws[OFF_DP + (n0+t)*64 + tid] = v;
            dprow[t][tid] = v;
        }
    }
    __syncthreads();
    {   // whh[h][d] = hp[h] @ Wh_w^T + b
        int h = tid >> 5, d = tid & 31;
        const float* WT = ws + OFF_WHT;
        float acc[8] = {0,0,0,0,0,0,0,0};
        for (int k = 0; k < 32; k += 4) {
            float w0 = WT[(k  )*32+d], w1 = WT[(k+1)*32+d];
            float w2 = WT[(k+2)*32+d], w3 = WT[(k+3)*32+d];
            #pragma unroll
            for (int t = 0; t < 8; ++t) {
                float4 h4 = *(const float4*)&hprow[t][h*32+k];
                acc[t] += h4.x*w0 + h4.y*w1 + h4.z*w2 + h4.w*w3;
            }
        }
        float b = Wh_b[d];
        #pragma unroll
        for (int t = 0; t < 8; ++t) ws[OFF_WHH + (size_t)(n0+t)*256 + tid] = acc[t] + b;
    }
    if (tid < 16) {  // s_i / s_j
        int h = tid & 7; bool isj = tid >= 8;
        const float* ah = attn_w + (isj ? 32 : 0);
        const float* ad = attn_w + (isj ? 88 : 80);
        for (int t = 0; t < 8; ++t) {
            float s = 0.f;
            for (int k = 0; k < 32; ++k) s += hprow[t][h*32+k]*ah[k];
            for (int k = 0; k < 8;  ++k) s += dprow[t][h*8+k]*ad[k];
            ws[(isj ? OFF_SJ : OFF_SI) + (n0+t)*8 + h] = s;
        }
    }
}

// ---------------- K2: fused phase-1 row kernel (block per (b,i)) --------
__global__ __launch_bounds__(256, 4)
void k_phase1(const float* __restrict__ edge, float* __restrict__ ws,
              const float* __restrict__ outn_b, float* __restrict__ out_node) {
    __shared__ float sc[8*SC_PITCH];     // 8448 B
    __shared__ float GsT[8*GT_PITCH];    // 4224 B
    __shared__ float sjs[2048];          // 8192 B
    __shared__ float cEs[8], sirow[8], hinv[8];
    __shared__ float hprow[256];
    __shared__ float arow[256];
    int tid = threadIdx.x;
    int bl = blockIdx.x;           // b*256 + i
    int i = bl & 255;
    int base_b = bl & ~255;
    for (int idx = tid; idx < 8*GT_PITCH; idx += 256) GsT[idx] = ws[OFF_GT + idx];
    #pragma unroll
    for (int q = 0; q < 8; ++q) sjs[q*256+tid] = ws[OFF_SJ + base_b*8 + q*256 + tid];
    if (tid < 8) { cEs[tid] = ws[OFF_CE + tid]; sirow[tid] = ws[OFF_SI + bl*8 + tid]; }
    hprow[tid] = ws[OFF_HP + (size_t)bl*256 + tid];
    __syncthreads();

    {   // s_e: register-tiled G, 16-k slabs
        int jj = tid >> 3, h = tid & 7;
        const float* erow = edge + (size_t)bl*256*128;
        float acc[8] = {0,0,0,0,0,0,0,0};
        for (int kt = 0; kt < 128; kt += 16) {
            float g[16];
            #pragma unroll
            for (int q = 0; q < 4; ++q)
                *(float4*)&g[q*4] = *(const float4*)&GsT[h*GT_PITCH + kt + q*4];
            #pragma unroll
            for (int t = 0; t < 8; ++t) {
                const float* ev = erow + (size_t)(t*32+jj)*128 + kt;
                float4 e0 = ((const float4*)ev)[0];
                float4 e1 = ((const float4*)ev)[1];
                float4 e2 = ((const float4*)ev)[2];
                float4 e3 = ((const float4*)ev)[3];
                acc[t] += e0.x*g[0] + e0.y*g[1] + e0.z*g[2] + e0.w*g[3]
                        + e1.x*g[4] + e1.y*g[5] + e1.z*g[6] + e1.w*g[7]
                        + e2.x*g[8] + e2.y*g[9] + e2.z*g[10]+ e2.w*g[11]
                        + e3.x*g[12]+ e3.y*g[13]+ e3.z*g[14]+ e3.w*g[15];
            }
        }
        float ce = cEs[h], si = sirow[h];
        #pragma unroll
        for (int t = 0; t < 8; ++t) {
            int j = t*32 + jj;
            float s = acc[t] + ce + si + sjs[j*8+h];
            s = lrelu(s);
            if (j == i) s = -3.4028235e38f;
            sc[h*SC_PITCH + j] = s;
        }
    }
    __syncthreads();
    {   // softmax over j per head; 32 lanes per head
        int g = tid >> 5, lane = tid & 31;
        float m = -3.4028235e38f;
        #pragma unroll
        for (int t = 0; t < 8; ++t) m = fmaxf(m, sc[g*SC_PITCH + lane + 32*t]);
        for (int off = 16; off >= 1; off >>= 1) m = fmaxf(m, __shfl_xor(m, off, 32));
        float ssum = 0.f;
        #pragma unroll
        for (int t = 0; t < 8; ++t) {
            int j = lane + 32*t;
            float e = __expf(sc[g*SC_PITCH + j] - m);
            sc[g*SC_PITCH + j] = e;
            ssum += e;
        }
        for (int off = 16; off >= 1; off >>= 1) ssum += __shfl_xor(ssum, off, 32);
        if (lane == 0) hinv[g] = 1.f/ssum;
    }
    __syncthreads();
    {   // agg + residual + lrelu (4 independent accumulators)
        int hh = tid >> 5;
        const float* whh = ws + OFF_WHH + (size_t)base_b*256;
        const float* scr = sc + hh*SC_PITCH;
        float a0=0.f, a1=0.f, a2=0.f, a3=0.f;
        #pragma unroll 2
        for (int j = 0; j < 256; j += 4) {
            a0 += scr[j  ]*whh[(size_t)(j  )*256 + tid];
            a1 += scr[j+1]*whh[(size_t)(j+1)*256 + tid];
            a2 += scr[j+2]*whh[(size_t)(j+2)*256 + tid];
            a3 += scr[j+3]*whh[(size_t)(j+3)*256 + tid];
        }
        float acc = ((a0+a1)+(a2+a3)) * hinv[hh];
        arow[tid] = hprow[tid] + lrelu(acc);
    }
    __syncthreads();
    {   // new_node = arow @ outn_w^T + b  (transposed weight, coalesced)
        const float* WT = ws + OFF_WNT;
        float o0=0.f, o1=0.f, o2=0.f, o3=0.f;
        #pragma unroll 2
        for (int m = 0; m < 256; m += 4) {
            o0 += arow[m  ]*WT[(m  )*256 + tid];
            o1 += arow[m+1]*WT[(m+1)*256 + tid];
            o2 += arow[m+2]*WT[(m+2)*256 + tid];
            o3 += arow[m+3]*WT[(m+3)*256 + tid];
        }
        out_node[(size_t)bl*256 + tid] = outn_b[tid] + ((o0+o1)+(o2+o3));
    }
}

// ---------------- K3: phase-2 node precompute (8 nodes/block) -----------
__global__ __launch_bounds__(256)
void k_node2(const float* __restrict__ out_node, const float* __restrict__ diff,
             const float* __restrict__ Wn2_b, const float* __restrict__ Wd2_b,
             const float* __restrict__ edge_lin_w, float* __restrict__ ws) {
    __shared__ float nrow[8][256];
    __shared__ float drow[8][64];
    __shared__ float hp2[8][256];
    __shared__ float dp2[8][64];
    __shared__ float tij[2][8][128];
    int tid = threadIdx.x;
    int n0 = blockIdx.x * 8;
    #pragma unroll
    for (int t = 0; t < 8; ++t) nrow[t][tid] = out_node[(size_t)(n0+t)*256 + tid];
    if (tid < 64) {
        #pragma unroll
        for (int t = 0; t < 8; ++t) drow[t][tid] = diff[(n0+t)*64 + tid];
    }
    __syncthreads();
    {
        const float* WT = ws + OFF_WN2T;
        float acc[8] = {0,0,0,0,0,0,0,0};
        for (int k = 0; k < 256; k += 4) {
            float w0 = WT[(k  )*256+tid], w1 = WT[(k+1)*256+tid];
            float w2 = WT[(k+2)*256+tid], w3 = WT[(k+3)*256+tid];
            #pragma unroll
            for (int t = 0; t < 8; ++t) {
                float4 n4 = *(const float4*)&nrow[t][k];
                acc[t] += n4.x*w0 + n4.y*w1 + n4.z*w2 + n4.w*w3;
            }
        }
        float b = Wn2_b[tid];
        #pragma unroll
        for (int t = 0; t < 8; ++t) hp2[t][tid] = acc[t] + b;
    }
    if (tid < 64) {
        const float* WT = ws + OFF_WD2T;
        float acc[8] = {0,0,0,0,0,0,0,0};
        for (int k = 0; k < 64; k += 4) {
            float w0 = WT[(k  )*64+tid], w1 = WT[(k+1)*64+tid];
            float w2 = WT[(k+2)*64+tid], w3 = WT[(k+3)*64+tid];
            #pragma unroll
            for (int t = 0; t < 8; ++t) {
                float4 d4 = *(const float4*)&drow[t][k];
                acc[t] += d4.x*w0 + d4.y*w1 + d4.z*w2 + d4.w*w3;
            }
        }
        float b = Wd2_b[tid];
        #pragma unroll
        for (int t = 0; t < 8; ++t) dp2[t][tid] = acc[t] + b;
    }
    __syncthreads();
    // t_i (s=0) / t_j (s=1)
    for (int q = 0; q < 8; ++q) {
        int idx = q*256 + tid;
        int s = idx >> 10; int r = idx & 1023; int t = r >> 7; int m = r & 127;
        int h = m >> 4, eo = m & 15;
        const float* wh = edge_lin_w + eo*96 + (s ? 48 : 16);
        const float* wd = edge_lin_w + eo*96 + (s ? 88 : 80);
        float v = 0.f;
        for (int d = 0; d < 32; ++d) v += hp2[t][h*32+d]*wh[d];
        for (int d = 0; d < 8;  ++d) v += dp2[t][h*8+d]*wd[d];
        tij[s][t][m] = v;
    }
    __syncthreads();
    // u = t_i @ oute_w^T ; v = t_j @ oute_w^T  (transposed, coalesced)
    for (int q = 0; q < 8; ++q) {
        int idx = q*256 + tid;
        int s = idx >> 10; int r = idx & 1023; int t = r >> 7; int n2 = r & 127;
        const float* OT = ws + OFF_OUTET;
        const float* tv = tij[s][t];
        float a0 = 0.f, a1 = 0.f;
        #pragma unroll 2
        for (int m = 0; m < 128; m += 2) {
            a0 += tv[m  ]*OT[(m  )*128 + n2];
            a1 += tv[m+1]*OT[(m+1)*128 + n2];
        }
        ws[(s ? OFF_V : OFF_U) + (n0+t)*128 + n2] = a0 + a1;
    }
}

// ---------------- K4: new_edge = edge@CT + u + v + k0 (diag -> oute_b) --
#define KKSTEP(F, KOFF) { \
    float4 b0 = *(const float4*)&CTs[(kq+KOFF)*128 + n2b]; \
    float4 b1 = *(const float4*)&CTs[(kq+KOFF)*128 + n2b + 4]; \
    _Pragma("unroll") \
    for (int p = 0; p < 8; ++p) { float av = a4[p].F; \
        acc[p][0] += av*b0.x; acc[p][1] += av*b0.y; acc[p][2] += av*b0.z; acc[p][3] += av*b0.w; \
        acc[p][4] += av*b1.x; acc[p][5] += av*b1.y; acc[p][6] += av*b1.z; acc[p][7] += av*b1.w; } }

__global__ __launch_bounds__(256, 2)
void k_edge2(const float* __restrict__ edge, const float* __restrict__ oute_b,
             const float* __restrict__ ws, float* __restrict__ out_edge) {
    __shared__ float CTs[128*128];   // 64 KB
    int tid = threadIdx.x;
    int bx = blockIdx.x;
    int bl = bx >> 1, jh = bx & 1;   // bl = b*256+i ; jh = j-half
    int i = bl & 255, base_b = bl & ~255;
    for (int idx = tid; idx < 16384; idx += 256) CTs[idx] = ws[OFF_CT + idx];
    __syncthreads();
    int tj = tid >> 4, tn = tid & 15;
    int n2b = tn*8;
    const float* erow = edge + (size_t)bl*256*128 + (size_t)(jh*128 + tj*8)*128;
    float acc[8][8];
    #pragma unroll
    for (int p = 0; p < 8; ++p)
        #pragma unroll
        for (int q = 0; q < 8; ++q) acc[p][q] = 0.f;

    for (int kq = 0; kq < 128; kq += 4) {
        float4 a4[8];
        #pragma unroll
        for (int p = 0; p < 8; ++p) a4[p] = *(const float4*)(erow + (size_t)p*128 + kq);
        KKSTEP(x, 0) KKSTEP(y, 1) KKSTEP(z, 2) KKSTEP(w, 3)
    }

    const float* uP = ws + OFF_U + (size_t)bl*128 + n2b;
    float4 u0 = *(const float4*)uP, u1 = *(const float4*)(uP+4);
    const float* cP = ws + OFF_K0 + n2b;
    float4 c0 = *(const float4*)cP, c1 = *(const float4*)(cP+4);
    float4 ob0 = *(const float4*)(oute_b + n2b), ob1 = *(const float4*)(oute_b + n2b + 4);
    #pragma unroll
    for (int p = 0; p < 8; ++p) {
        int j = jh*128 + tj*8 + p;
        const float* vP = ws + OFF_V + (size_t)(base_b + j)*128 + n2b;
        float4 v0 = *(const float4*)vP, v1 = *(const float4*)(vP+4);
        float4 o0, o1;
        o0.x = acc[p][0]+u0.x+v0.x+c0.x; o0.y = acc[p][1]+u0.y+v0.y+c0.y;
        o0.z = acc[p][2]+u0.z+v0.z+c0.z; o0.w = acc[p][3]+u0.w+v0.w+c0.w;
        o1.x = acc[p][4]+u1.x+v1.x+c1.x; o1.y = acc[p][5]+u1.y+v1.y+c1.y;
        o1.z = acc[p][6]+u1.z+v1.z+c1.z; o1.w = acc[p][7]+u1.w+v1.w+c1.w;
        if (j == i) { o0 = ob0; o1 = ob1; }
        float* oP = out_edge + ((size_t)bl*256 + j)*128 + n2b;
        *(float4*)oP = o0; *(float4*)(oP+4) = o1;
    }
}

// ---------------- launch ------------------------------------------------
extern "C" void kernel_launch(void* const* d_in, const int* in_sizes, int n_in,
                              void* d_out, int out_size, void* d_ws, size_t ws_size,
                              hipStream_t stream) {
    const float* node   = (const float*)d_in[0];
    const float* edge   = (const float*)d_in[1];
    const float* diff   = (const float*)d_in[2];
    const float* Wn_w   = (const float*)d_in[3];
    const float* Wn_b   = (const float*)d_in[4];
    const float* Wh_w   = (const float*)d_in[5];
    const float* Wh_b   = (const float*)d_in[6];
    const float* We_w   = (const float*)d_in[7];
    const float* We_b   = (const float*)d_in[8];
    const float* Wn2_w  = (const float*)d_in[9];
    const float* Wn2_b  = (const float*)d_in[10];
    const float* We2_w  = (const float*)d_in[11];
    const float* We2_b  = (const float*)d_in[12];
    const float* Wd_w   = (const float*)d_in[13];
    const float* Wd_b   = (const float*)d_in[14];
    const float* Wd2_w  = (const float*)d_in[15];
    const float* Wd2_b  = (const float*)d_in[16];
    const float* attn_w = (const float*)d_in[17];
    const float* elw    = (const float*)d_in[18];
    const float* elb    = (const float*)d_in[19];
    const float* outn_w = (const float*)d_in[20];
    const float* outn_b = (const float*)d_in[21];
    const float* oute_w = (const float*)d_in[22];
    const float* oute_b = (const float*)d_in[23];
    float* ws = (float*)d_ws;
    float* out_node = (float*)d_out;
    float* out_edge = out_node + (size_t)NODE_CNT*256;

    k_pre_a<<<1, 256, 0, stream>>>(We_w, We_b, attn_w, elw, elb, We2_w, We2_b, ws);
    k_pre_b<<<64, 256, 0, stream>>>(oute_w, oute_b, ws);
    k_transpose<<<868, 256, 0, stream>>>(Wn_w, Wn2_w, outn_w, oute_w, Wd_w, Wd2_w, Wh_w, ws);
    k_node1<<<256, 256, 0, stream>>>(node, diff, Wn_b, Wd_b, Wh_b, attn_w, ws);
    k_phase1<<<NODE_CNT, 256, 0, stream>>>(edge, ws, outn_b, out_node);
    k_node2<<<256, 256, 0, stream>>>(out_node, diff, Wn2_b, Wd2_b, elw, ws);
    k_edge2<<<NODE_CNT*2, 256, 0, stream>>>(edge, oute_b, ws, out_edge);
}

// Round 4
// 790.244 us; speedup vs baseline: 1.3803x; 1.1605x over previous
//
#include <hip/hip_runtime.h>
#include <cstdint>
#include <cstddef>

// Shapes (fixed)
#define NBATCH 8
#define LSEQ   256
#define NODE_CNT 2048   // NBATCH*LSEQ

// workspace float offsets
#define OFF_HP      0u         // 2048*256
#define OFF_DP      524288u    // 2048*64
#define OFF_SI      655360u    // 2048*8
#define OFF_SJ      671744u    // 2048*8
#define OFF_WHH     688128u    // 2048*256
#define OFF_U       1212416u   // 2048*128
#define OFF_V       1474560u   // 2048*128
#define OFF_CE      1737728u   // 8 (padded)
#define OFF_CT      1737760u   // 128*128
#define OFF_K0      1754144u   // 128
#define OFF_D       1754272u   // 128*128 (dead after k_pre_b; reused:)
#define OFF_CTH     1754272u   //   128*128 ushort bf16-hi CT^T  (8192 floats)
#define OFF_CTL     1762464u   //   128*128 ushort bf16-lo CT^T  (8192 floats)
#define OFF_CONSTE  1770656u   // 128
#define OFF_GT      1770784u   // 8*132 (G transposed, padded pitch)
#define OFF_WN1T    1771840u   // 256*256 Wn_w^T
#define OFF_WN2T    1837376u   // 256*256 Wn2_w^T
#define OFF_WNT     1902912u   // 256*256 outn_w^T
#define OFF_OUTET   1968448u   // 128*128 oute_w^T
#define OFF_WD1T    1984832u   // 64*64
#define OFF_WD2T    1988928u   // 64*64
#define OFF_WHT     1993024u   // 32*32
// total 1994048 floats ~= 8.0 MB

#define GT_PITCH 132
#define SC_PITCH 264

typedef __attribute__((ext_vector_type(8))) __bf16 bf16x8;
typedef __attribute__((ext_vector_type(8))) unsigned short ushort8;
typedef __attribute__((ext_vector_type(4))) float f32x4;
typedef __attribute__((ext_vector_type(4))) unsigned int u32x4;

__device__ __forceinline__ float lrelu(float x){ return x >= 0.f ? x : 0.2f*x; }

// ---------------- K0c: weight transposes (FIRST: k_pre_b needs OUTET) ----
__global__ void k_transpose(const float* __restrict__ Wn_w, const float* __restrict__ Wn2_w,
                            const float* __restrict__ outn_w, const float* __restrict__ oute_w,
                            const float* __restrict__ Wd_w, const float* __restrict__ Wd2_w,
                            const float* __restrict__ Wh_w, float* __restrict__ ws) {
    int bx = blockIdx.x, tid = threadIdx.x;
    const float* src; float* dst; int ln, base;
    if      (bx < 256) { src = Wn_w;   dst = ws + OFF_WN1T;  ln = 8; base = bx; }
    else if (bx < 512) { src = Wn2_w;  dst = ws + OFF_WN2T;  ln = 8; base = bx - 256; }
    else if (bx < 768) { src = outn_w; dst = ws + OFF_WNT;   ln = 8; base = bx - 512; }
    else if (bx < 832) { src = oute_w; dst = ws + OFF_OUTET; ln = 7; base = bx - 768; }
    else if (bx < 848) { src = Wd_w;   dst = ws + OFF_WD1T;  ln = 6; base = bx - 832; }
    else if (bx < 864) { src = Wd2_w;  dst = ws + OFF_WD2T;  ln = 6; base = bx - 848; }
    else               { src = Wh_w;   dst = ws + OFF_WHT;   ln = 5; base = bx - 864; }
    int idx = base*256 + tid;
    int N = 1 << ln;
    int k = idx >> ln, n = idx & (N-1);
    dst[idx] = src[n*N + k];     // dst[k*N+n] = src[n][k]
}

// ---------------- K0a: fold attention vector + phase-2 left chain ----------
__global__ void k_pre_a(const float* __restrict__ We_w, const float* __restrict__ We_b,
                        const float* __restrict__ attn_w,
                        const float* __restrict__ edge_lin_w, const float* __restrict__ edge_lin_b,
                        const float* __restrict__ We2_w, const float* __restrict__ We2_b,
                        float* __restrict__ ws) {
    int tid = threadIdx.x;
    const float* a_e = attn_w + 64;  // a[64:80]
    // GT[h][k] = sum_e a_e[e]*We_w[h*16+e][k]   (k fast axis -> coalesced)
    for (int idx = tid; idx < 128*8; idx += 256) {
        int h = idx >> 7, k = idx & 127;
        float s = 0.f;
        for (int e = 0; e < 16; ++e) s += a_e[e] * We_w[(h*16+e)*128 + k];
        ws[OFF_GT + h*GT_PITCH + k] = s;
    }
    if (tid < 8) {
        float s = 0.f;
        for (int e = 0; e < 16; ++e) s += a_e[e] * We_b[tid*16+e];
        ws[OFF_CE + tid] = s;
    }
    // D[m=h*16+eo][k] = sum_ei W_e[eo][ei]*We2_w[h*16+ei][k]
    for (int idx = tid; idx < 128*128; idx += 256) {
        int m = idx >> 7, k = idx & 127;
        int h = m >> 4, eo = m & 15;
        float s = 0.f;
        for (int ei = 0; ei < 16; ++ei) s += edge_lin_w[eo*96 + ei] * We2_w[(h*16+ei)*128 + k];
        ws[OFF_D + m*128 + k] = s;
    }
    if (tid < 128) {
        int h = tid >> 4, eo = tid & 15;
        float s = edge_lin_b[eo];
        for (int ei = 0; ei < 16; ++ei) s += edge_lin_w[eo*96+ei] * We2_b[h*16+ei];
        ws[OFF_CONSTE + tid] = s;
    }
}

// ---------------- K0b: CT = (oute_w @ D)^T, k0 (uses OUTET, coalesced) ---
__global__ void k_pre_b(const float* __restrict__ oute_b, float* __restrict__ ws) {
    int idx = blockIdx.x*256 + threadIdx.x;  // 0..16383
    int k = idx >> 7, n2 = idx & 127;
    const float* D  = ws + OFF_D;
    const float* OT = ws + OFF_OUTET;        // OT[m*128+n] = oute_w[n][m]
    float s = 0.f;
    for (int m = 0; m < 128; ++m) s += OT[m*128+n2] * D[m*128+k];
    ws[OFF_CT + k*128 + n2] = s;
    if (blockIdx.x == 0 && threadIdx.x < 128) {
        int n = threadIdx.x;
        float t = oute_b[n];
        const float* ce = ws + OFF_CONSTE;
        for (int m = 0; m < 128; ++m) t += OT[m*128+n]*ce[m];
        ws[OFF_K0 + n] = t;
    }
}

// ---------------- K0d: CT -> bf16 hi/lo, transposed [n][k] ---------------
__global__ void k_pre_c(float* __restrict__ ws) {
    int idx = blockIdx.x*256 + threadIdx.x;  // 16384
    int k = idx >> 7, n = idx & 127;
    float s = ws[OFF_CT + k*128 + n];
    unsigned int u = __builtin_bit_cast(unsigned int, s);
    unsigned int h = u >> 16;                               // trunc hi
    float fh = __builtin_bit_cast(float, h << 16);
    float rem = s - fh;
    unsigned short lo = (unsigned short)(__builtin_bit_cast(unsigned int, rem) >> 16);
    unsigned short* cth = (unsigned short*)(ws + OFF_CTH);
    unsigned short* ctl = (unsigned short*)(ws + OFF_CTL);
    cth[n*128 + k] = (unsigned short)h;
    ctl[n*128 + k] = lo;
}

// ---------------- K1: per-node phase-1 projections (8 nodes/block) ------
__global__ __launch_bounds__(256)
void k_node1(const float* __restrict__ node, const float* __restrict__ diff,
             const float* __restrict__ Wn_b, const float* __restrict__ Wd_b,
             const float* __restrict__ Wh_b, const float* __restrict__ attn_w,
             float* __restrict__ ws) {
    __shared__ float nrow[8][256];
    __shared__ float drow[8][64];
    __shared__ float hprow[8][256];
    __shared__ float dprow[8][64];
    int tid = threadIdx.x;
    int n0 = blockIdx.x * 8;
    #pragma unroll
    for (int t = 0; t < 8; ++t) nrow[t][tid] = node[(size_t)(n0+t)*256 + tid];
    if (tid < 64) {
        #pragma unroll
        for (int t = 0; t < 8; ++t) drow[t][tid] = diff[(n0+t)*64 + tid];
    }
    __syncthreads();
    {   // hp = node @ Wn_w^T + b  (WT coalesced, nrow broadcast)
        const float* WT = ws + OFF_WN1T;
        float acc[8] = {0,0,0,0,0,0,0,0};
        for (int k = 0; k < 256; k += 4) {
            float w0 = WT[(k  )*256+tid], w1 = WT[(k+1)*256+tid];
            float w2 = WT[(k+2)*256+tid], w3 = WT[(k+3)*256+tid];
            #pragma unroll
            for (int t = 0; t < 8; ++t) {
                float4 n4 = *(const float4*)&nrow[t][k];
                acc[t] += n4.x*w0 + n4.y*w1 + n4.z*w2 + n4.w*w3;
            }
        }
        float b = Wn_b[tid];
        #pragma unroll
        for (int t = 0; t < 8; ++t) {
            float v = acc[t] + b;
            ws[OFF_HP + (size_t)(n0+t)*256 + tid] = v;
            hprow[t][tid] = v;
        }
    }
    if (tid < 64) {  // dp = diff @ Wd_w^T + b
        const float* WT = ws + OFF_WD1T;
        float acc[8] = {0,0,0,0,0,0,0,0};
        for (int k = 0; k < 64; k += 4) {
            float w0 = WT[(k  )*64+tid], w1 = WT[(k+1)*64+tid];
            float w2 = WT[(k+2)*64+tid], w3 = WT[(k+3)*64+tid];
            #pragma unroll
            for (int t = 0; t < 8; ++t) {
                float4 d4 = *(const float4*)&drow[t][k];
                acc[t] += d4.x*w0 + d4.y*w1 + d4.z*w2 + d4.w*w3;
            }
        }
        float b = Wd_b[tid];
        #pragma unroll
        for (int t = 0; t < 8; ++t) {
            float v = acc[t] + b;
            ws[OFF_DP + (n0+t)*64 + tid] = v;
            dprow[t][tid] = v;
        }
    }
    __syncthreads();
    {   // whh[h][d] = hp[h] @ Wh_w^T + b
        int h = tid >> 5, d = tid & 31;
        const float* WT = ws + OFF_WHT;
        float acc[8] = {0,0,0,0,0,0,0,0};
        for (int k = 0; k < 32; k += 4) {
            float w0 = WT[(k  )*32+d], w1 = WT[(k+1)*32+d];
            float w2 = WT[(k+2)*32+d], w3 = WT[(k+3)*32+d];
            #pragma unroll
            for (int t = 0; t < 8; ++t) {
                float4 h4 = *(const float4*)&hprow[t][h*32+k];
                acc[t] += h4.x*w0 + h4.y*w1 + h4.z*w2 + h4.w*w3;
            }
        }
        float b = Wh_b[d];
        #pragma unroll
        for (int t = 0; t < 8; ++t) ws[OFF_WHH + (size_t)(n0+t)*256 + tid] = acc[t] + b;
    }
    if (tid < 16) {  // s_i / s_j
        int h = tid & 7; bool isj = tid >= 8;
        const float* ah = attn_w + (isj ? 32 : 0);
        const float* ad = attn_w + (isj ? 88 : 80);
        for (int t = 0; t < 8; ++t) {
            float s = 0.f;
            for (int k = 0; k < 32; ++k) s += hprow[t][h*32+k]*ah[k];
            for (int k = 0; k < 8;  ++k) s += dprow[t][h*8+k]*ad[k];
            ws[(isj ? OFF_SJ : OFF_SI) + (n0+t)*8 + h] = s;
        }
    }
}

// ---------------- K2: fused phase-1 row kernel (block per (b,i)) --------
__global__ __launch_bounds__(256, 4)
void k_phase1(const float* __restrict__ edge, float* __restrict__ ws,
              const float* __restrict__ outn_b, float* __restrict__ out_node) {
    __shared__ float sc[8*SC_PITCH];     // 8448 B
    __shared__ float GsT[8*GT_PITCH];    // 4224 B
    __shared__ float sjs[2048];          // 8192 B
    __shared__ float cEs[8], sirow[8], hinv[8];
    __shared__ float hprow[256];
    __shared__ float arow[256];
    int tid = threadIdx.x;
    int bl = blockIdx.x;           // b*256 + i
    int i = bl & 255;
    int base_b = bl & ~255;
    for (int idx = tid; idx < 8*GT_PITCH; idx += 256) GsT[idx] = ws[OFF_GT + idx];
    #pragma unroll
    for (int q = 0; q < 8; ++q) sjs[q*256+tid] = ws[OFF_SJ + base_b*8 + q*256 + tid];
    if (tid < 8) { cEs[tid] = ws[OFF_CE + tid]; sirow[tid] = ws[OFF_SI + bl*8 + tid]; }
    hprow[tid] = ws[OFF_HP + (size_t)bl*256 + tid];
    __syncthreads();

    {   // s_e: register-tiled G, 16-k slabs
        int jj = tid >> 3, h = tid & 7;
        const float* erow = edge + (size_t)bl*256*128;
        float acc[8] = {0,0,0,0,0,0,0,0};
        for (int kt = 0; kt < 128; kt += 16) {
            float g[16];
            #pragma unroll
            for (int q = 0; q < 4; ++q)
                *(float4*)&g[q*4] = *(const float4*)&GsT[h*GT_PITCH + kt + q*4];
            #pragma unroll
            for (int t = 0; t < 8; ++t) {
                const float* ev = erow + (size_t)(t*32+jj)*128 + kt;
                float4 e0 = ((const float4*)ev)[0];
                float4 e1 = ((const float4*)ev)[1];
                float4 e2 = ((const float4*)ev)[2];
                float4 e3 = ((const float4*)ev)[3];
                acc[t] += e0.x*g[0] + e0.y*g[1] + e0.z*g[2] + e0.w*g[3]
                        + e1.x*g[4] + e1.y*g[5] + e1.z*g[6] + e1.w*g[7]
                        + e2.x*g[8] + e2.y*g[9] + e2.z*g[10]+ e2.w*g[11]
                        + e3.x*g[12]+ e3.y*g[13]+ e3.z*g[14]+ e3.w*g[15];
            }
        }
        float ce = cEs[h], si = sirow[h];
        #pragma unroll
        for (int t = 0; t < 8; ++t) {
            int j = t*32 + jj;
            float s = acc[t] + ce + si + sjs[j*8+h];
            s = lrelu(s);
            if (j == i) s = -3.4028235e38f;
            sc[h*SC_PITCH + j] = s;
        }
    }
    __syncthreads();
    {   // softmax over j per head; 32 lanes per head
        int g = tid >> 5, lane = tid & 31;
        float m = -3.4028235e38f;
        #pragma unroll
        for (int t = 0; t < 8; ++t) m = fmaxf(m, sc[g*SC_PITCH + lane + 32*t]);
        for (int off = 16; off >= 1; off >>= 1) m = fmaxf(m, __shfl_xor(m, off, 32));
        float ssum = 0.f;
        #pragma unroll
        for (int t = 0; t < 8; ++t) {
            int j = lane + 32*t;
            float e = __expf(sc[g*SC_PITCH + j] - m);
            sc[g*SC_PITCH + j] = e;
            ssum += e;
        }
        for (int off = 16; off >= 1; off >>= 1) ssum += __shfl_xor(ssum, off, 32);
        if (lane == 0) hinv[g] = 1.f/ssum;
    }
    __syncthreads();
    {   // agg + residual + lrelu (4 independent accumulators)
        int hh = tid >> 5;
        const float* whh = ws + OFF_WHH + (size_t)base_b*256;
        const float* scr = sc + hh*SC_PITCH;
        float a0=0.f, a1=0.f, a2=0.f, a3=0.f;
        #pragma unroll 2
        for (int j = 0; j < 256; j += 4) {
            a0 += scr[j  ]*whh[(size_t)(j  )*256 + tid];
            a1 += scr[j+1]*whh[(size_t)(j+1)*256 + tid];
            a2 += scr[j+2]*whh[(size_t)(j+2)*256 + tid];
            a3 += scr[j+3]*whh[(size_t)(j+3)*256 + tid];
        }
        float acc = ((a0+a1)+(a2+a3)) * hinv[hh];
        arow[tid] = hprow[tid] + lrelu(acc);
    }
    __syncthreads();
    {   // new_node = arow @ outn_w^T + b  (transposed weight, coalesced)
        const float* WT = ws + OFF_WNT;
        float o0=0.f, o1=0.f, o2=0.f, o3=0.f;
        #pragma unroll 2
        for (int m = 0; m < 256; m += 4) {
            o0 += arow[m  ]*WT[(m  )*256 + tid];
            o1 += arow[m+1]*WT[(m+1)*256 + tid];
            o2 += arow[m+2]*WT[(m+2)*256 + tid];
            o3 += arow[m+3]*WT[(m+3)*256 + tid];
        }
        out_node[(size_t)bl*256 + tid] = outn_b[tid] + ((o0+o1)+(o2+o3));
    }
}

// ---------------- K3: phase-2 node precompute (8 nodes/block) -----------
__global__ __launch_bounds__(256)
void k_node2(const float* __restrict__ out_node, const float* __restrict__ diff,
             const float* __restrict__ Wn2_b, const float* __restrict__ Wd2_b,
             const float* __restrict__ edge_lin_w, float* __restrict__ ws) {
    __shared__ float nrow[8][256];
    __shared__ float drow[8][64];
    __shared__ float hp2[8][256];
    __shared__ float dp2[8][64];
    __shared__ float tij[2][8][128];
    int tid = threadIdx.x;
    int n0 = blockIdx.x * 8;
    #pragma unroll
    for (int t = 0; t < 8; ++t) nrow[t][tid] = out_node[(size_t)(n0+t)*256 + tid];
    if (tid < 64) {
        #pragma unroll
        for (int t = 0; t < 8; ++t) drow[t][tid] = diff[(n0+t)*64 + tid];
    }
    __syncthreads();
    {
        const float* WT = ws + OFF_WN2T;
        float acc[8] = {0,0,0,0,0,0,0,0};
        for (int k = 0; k < 256; k += 4) {
            float w0 = WT[(k  )*256+tid], w1 = WT[(k+1)*256+tid];
            float w2 = WT[(k+2)*256+tid], w3 = WT[(k+3)*256+tid];
            #pragma unroll
            for (int t = 0; t < 8; ++t) {
                float4 n4 = *(const float4*)&nrow[t][k];
                acc[t] += n4.x*w0 + n4.y*w1 + n4.z*w2 + n4.w*w3;
            }
        }
        float b = Wn2_b[tid];
        #pragma unroll
        for (int t = 0; t < 8; ++t) hp2[t][tid] = acc[t] + b;
    }
    if (tid < 64) {
        const float* WT = ws + OFF_WD2T;
        float acc[8] = {0,0,0,0,0,0,0,0};
        for (int k = 0; k < 64; k += 4) {
            float w0 = WT[(k  )*64+tid], w1 = WT[(k+1)*64+tid];
            float w2 = WT[(k+2)*64+tid], w3 = WT[(k+3)*64+tid];
            #pragma unroll
            for (int t = 0; t < 8; ++t) {
                float4 d4 = *(const float4*)&drow[t][k];
                acc[t] += d4.x*w0 + d4.y*w1 + d4.z*w2 + d4.w*w3;
            }
        }
        float b = Wd2_b[tid];
        #pragma unroll
        for (int t = 0; t < 8; ++t) dp2[t][tid] = acc[t] + b;
    }
    __syncthreads();
    // t_i (s=0) / t_j (s=1)
    for (int q = 0; q < 8; ++q) {
        int idx = q*256 + tid;
        int s = idx >> 10; int r = idx & 1023; int t = r >> 7; int m = r & 127;
        int h = m >> 4, eo = m & 15;
        const float* wh = edge_lin_w + eo*96 + (s ? 48 : 16);
        const float* wd = edge_lin_w + eo*96 + (s ? 88 : 80);
        float v = 0.f;
        for (int d = 0; d < 32; ++d) v += hp2[t][h*32+d]*wh[d];
        for (int d = 0; d < 8;  ++d) v += dp2[t][h*8+d]*wd[d];
        tij[s][t][m] = v;
    }
    __syncthreads();
    // u = t_i @ oute_w^T ; v = t_j @ oute_w^T  (transposed, coalesced)
    for (int q = 0; q < 8; ++q) {
        int idx = q*256 + tid;
        int s = idx >> 10; int r = idx & 1023; int t = r >> 7; int n2 = r & 127;
        const float* OT = ws + OFF_OUTET;
        const float* tv = tij[s][t];
        float a0 = 0.f, a1 = 0.f;
        #pragma unroll 2
        for (int m = 0; m < 128; m += 2) {
            a0 += tv[m  ]*OT[(m  )*128 + n2];
            a1 += tv[m+1]*OT[(m+1)*128 + n2];
        }
        ws[(s ? OFF_V : OFF_U) + (n0+t)*128 + n2] = a0 + a1;
    }
}

// ---------------- K4: new_edge = edge@CT + u + v + k0 via bf16-split MFMA
// Block: 512 thr (8 waves). Wave w: rows [w*32, w*32+32), full N=128.
// CT^T (bf16 hi/lo) staged in LDS with XOR swizzle byte^=((n&7)<<4).
__global__ __launch_bounds__(512, 4)
void k_edge2(const float* __restrict__ edge, const float* __restrict__ oute_b,
             const float* __restrict__ ws, float* __restrict__ out_edge) {
    __shared__ __align__(16) char smem[65536];   // [0,32K): CT^T hi, [32K,64K): lo
    int tid = threadIdx.x;
    int bl = blockIdx.x;             // b*256 + i
    int i = bl & 255, base_b = bl & ~255;

    {   // stage CT^T hi/lo, swizzled (16B chunks; 2-way bank max)
        const u32x4* srcH = (const u32x4*)(ws + OFF_CTH);
        const u32x4* srcL = (const u32x4*)(ws + OFF_CTL);
        for (int c = tid; c < 2048; c += 512) {
            int n = c >> 4;
            int off = ((n << 8) + ((c & 15) << 4)) ^ ((n & 7) << 4);
            *(u32x4*)(smem + off)         = srcH[c];
            *(u32x4*)(smem + 32768 + off) = srcL[c];
        }
    }
    __syncthreads();

    int w = tid >> 6, l = tid & 63;
    int col = l & 15, kq = l >> 4;             // kq in 0..3
    int r0 = w * 32;
    const float* eb = edge + (size_t)bl * 32768;   // 256*128
    int swz = (col & 7) << 4;

    f32x4 acc[2][8] = {};

    #pragma unroll
    for (int ks = 0; ks < 4; ++ks) {
        // A: load 8 fp32 per m-tile, split to bf16 hi/lo (truncation split)
        bf16x8 ah[2], al[2];
        #pragma unroll
        for (int mt = 0; mt < 2; ++mt) {
            const float* ap = eb + (size_t)(r0 + mt*16 + col) * 128 + ks*32 + kq*8;
            float4 e0 = *(const float4*)ap;
            float4 e1 = *(const float4*)(ap + 4);
            float ev[8] = {e0.x, e0.y, e0.z, e0.w, e1.x, e1.y, e1.z, e1.w};
            ushort8 hs, ls;
            #pragma unroll
            for (int q = 0; q < 8; ++q) {
                unsigned int u = __builtin_bit_cast(unsigned int, ev[q]);
                unsigned int h = u >> 16;
                float fh = __builtin_bit_cast(float, h << 16);
                float rem = ev[q] - fh;
                hs[q] = (unsigned short)h;
                ls[q] = (unsigned short)(__builtin_bit_cast(unsigned int, rem) >> 16);
            }
            ah[mt] = __builtin_bit_cast(bf16x8, hs);
            al[mt] = __builtin_bit_cast(bf16x8, ls);
        }
        // B: ds_read_b128 per n-tile (hi & lo)
        bf16x8 bh[8], blo[8];
        #pragma unroll
        for (int nt = 0; nt < 8; ++nt) {
            int n = nt*16 + col;
            int off = ((n << 8) + (ks << 6) + (kq << 4)) ^ swz;
            bh[nt]  = __builtin_bit_cast(bf16x8, *(const u32x4*)(smem + off));
            blo[nt] = __builtin_bit_cast(bf16x8, *(const u32x4*)(smem + 32768 + off));
        }
        // 3-term split MFMA
        #pragma unroll
        for (int nt = 0; nt < 8; ++nt) {
            #pragma unroll
            for (int mt = 0; mt < 2; ++mt) {
                acc[mt][nt] = __builtin_amdgcn_mfma_f32_16x16x32_bf16(ah[mt], bh[nt],  acc[mt][nt], 0, 0, 0);
                acc[mt][nt] = __builtin_amdgcn_mfma_f32_16x16x32_bf16(al[mt], bh[nt],  acc[mt][nt], 0, 0, 0);
                acc[mt][nt] = __builtin_amdgcn_mfma_f32_16x16x32_bf16(ah[mt], blo[nt], acc[mt][nt], 0, 0, 0);
            }
        }
    }

    // epilogue: + u + k0 + v ; diag row -> oute_b
    float uk[8], ob[8];
    #pragma unroll
    for (int nt = 0; nt < 8; ++nt) {
        int n = nt*16 + col;
        uk[nt] = ws[OFF_U + (size_t)bl*128 + n] + ws[OFF_K0 + n];
        ob[nt] = oute_b[n];
    }
    #pragma unroll
    for (int mt = 0; mt < 2; ++mt) {
        #pragma unroll
        for (int q = 0; q < 4; ++q) {
            int jrow = r0 + mt*16 + kq*4 + q;        // D row = (l>>4)*4 + reg
            const float* vrow = ws + OFF_V + (size_t)(base_b + jrow)*128;
            float* orow = out_edge + ((size_t)bl*256 + jrow)*128;
            bool diag = (jrow == i);
            #pragma unroll
            for (int nt = 0; nt < 8; ++nt) {
                int n = nt*16 + col;
                float val = acc[mt][nt][q] + uk[nt] + vrow[n];
                orow[n] = diag ? ob[nt] : val;
            }
        }
    }
}

// ---------------- launch ------------------------------------------------
extern "C" void kernel_launch(void* const* d_in, const int* in_sizes, int n_in,
                              void* d_out, int out_size, void* d_ws, size_t ws_size,
                              hipStream_t stream) {
    const float* node   = (const float*)d_in[0];
    const float* edge   = (const float*)d_in[1];
    const float* diff   = (const float*)d_in[2];
    const float* Wn_w   = (const float*)d_in[3];
    const float* Wn_b   = (const float*)d_in[4];
    const float* Wh_w   = (const float*)d_in[5];
    const float* Wh_b   = (const float*)d_in[6];
    const float* We_w   = (const float*)d_in[7];
    const float* We_b   = (const float*)d_in[8];
    const float* Wn2_w  = (const float*)d_in[9];
    const float* Wn2_b  = (const float*)d_in[10];
    const float* We2_w  = (const float*)d_in[11];
    const float* We2_b  = (const float*)d_in[12];
    const float* Wd_w   = (const float*)d_in[13];
    const float* Wd_b   = (const float*)d_in[14];
    const float* Wd2_w  = (const float*)d_in[15];
    const float* Wd2_b  = (const float*)d_in[16];
    const float* attn_w = (const float*)d_in[17];
    const float* elw    = (const float*)d_in[18];
    const float* elb    = (const float*)d_in[19];
    const float* outn_w = (const float*)d_in[20];
    const float* outn_b = (const float*)d_in[21];
    const float* oute_w = (const float*)d_in[22];
    const float* oute_b = (const float*)d_in[23];
    float* ws = (float*)d_ws;
    float* out_node = (float*)d_out;
    float* out_edge = out_node + (size_t)NODE_CNT*256;

    k_transpose<<<868, 256, 0, stream>>>(Wn_w, Wn2_w, outn_w, oute_w, Wd_w, Wd2_w, Wh_w, ws);
    k_pre_a<<<1, 256, 0, stream>>>(We_w, We_b, attn_w, elw, elb, We2_w, We2_b, ws);
    k_pre_b<<<64, 256, 0, stream>>>(oute_b, ws);
    k_pre_c<<<64, 256, 0, stream>>>(ws);
    k_node1<<<256, 256, 0, stream>>>(node, diff, Wn_b, Wd_b, Wh_b, attn_w, ws);
    k_phase1<<<NODE_CNT, 256, 0, stream>>>(edge, ws, outn_b, out_node);
    k_node2<<<256, 256, 0, stream>>>(out_node, diff, Wn2_b, Wd2_b, elw, ws);
    k_edge2<<<NODE_CNT, 512, 0, stream>>>(edge, oute_b, ws, out_edge);
}